// Round 5
// baseline (107339.734 us; speedup 1.0000x reference)
//
#include <hip/hip_runtime.h>
#include <hip/hip_bf16.h>

#define S_ 512
#define B_ 128
#define D_ 128
#define H_ 512
#define NB_ 240
#define NGRP 8
#define GSZ 30

typedef short bf16x8 __attribute__((ext_vector_type(8)));
typedef int i32x4 __attribute__((ext_vector_type(4)));
typedef float f32x4 __attribute__((ext_vector_type(4)));

// ---- weight plane offsets (in shorts). 3 planes, plane stride WPLANE. ----
#define OFF0_XI   0
#define OFF0_HI   131072
#define OFF0_OX   655360
#define OFF0_OH   720896
#define OFF0_IO   983040
#define OFF0_HO   1245184
#define OFF0_CHO  1507328
#define OFF0_A    1769472
#define OFF0_B    2031616
#define OFF1_XI   2293760
#define OFF1_HI   2818048
#define OFF1_OX   3342336
#define OFF1_OH   3604480
#define OFF1_IO   3866624
#define OFF1_HO   4128768
#define OFF1_CHO  4390912
#define OFF1_A    4653056
#define OFF1_B    4915200
#define WPLANE    5177344
#define APLANE    65536

__device__ __forceinline__ float sigf(float x) { return 1.0f / (1.0f + expf(-x)); }

__device__ __forceinline__ short bfs(float v) {
  __hip_bfloat16 h = __float2bfloat16(v);
  return __builtin_bit_cast(short, h);
}
__device__ __forceinline__ float bff(short s) {
  __hip_bfloat16 h = __builtin_bit_cast(__hip_bfloat16, s);
  return __bfloat162float(h);
}

// ---- memory ops ----
// plain cached 16B load (L1/L2 allocate) — consumers, after acquire-inv
__device__ __forceinline__ i32x4 ldg16(const short* p) {
  i32x4 o;
  asm volatile("global_load_dwordx4 %0, %1, off" : "=v"(o) : "v"(p));
  return o;
}
// sc1 write-through store — producers (agent-visible after vmcnt(0), no dirty L2)
__device__ __forceinline__ void stg16_sc(short* p, unsigned int v) {
  asm volatile("global_store_short %0, %1, off sc1" ::"v"(p), "v"(v) : "memory");
}
#define VMDRAIN()                                       \
  do {                                                  \
    asm volatile("s_waitcnt vmcnt(0)" ::: "memory");    \
    __builtin_amdgcn_sched_barrier(0);                  \
  } while (0)

// split-store one fp32 as 3 bf16 planes, sc1-coherent
__device__ __forceinline__ void st3g(short* buf, int idx, float v) {
  short s0 = bfs(v);
  float f0 = bff(s0);
  float r1 = v - f0;
  short s1 = bfs(r1);
  float f1 = bff(s1);
  short s2 = bfs(r1 - f1);
  stg16_sc(buf + idx, (unsigned int)(unsigned short)s0);
  stg16_sc(buf + idx + APLANE, (unsigned int)(unsigned short)s1);
  stg16_sc(buf + idx + 2 * APLANE, (unsigned int)(unsigned short)s2);
}
// plain 3-plane gather (cached)
__device__ __forceinline__ float ld3p(const short* buf, int idx) {
  return bff(buf[idx]) + bff(buf[idx + APLANE]) + bff(buf[idx + 2 * APLANE]);
}

#define MFMA16(a, b, c) __builtin_amdgcn_mfma_f32_16x16x32_bf16(a, b, c, 0, 0, 0)

__device__ __forceinline__ void mac6(f32x4& acc, const bf16x8& a0, const bf16x8& a1,
                                     const bf16x8& a2, const bf16x8& W0,
                                     const bf16x8& W1, const bf16x8& W2) {
  acc = MFMA16(a0, W0, acc);
  acc = MFMA16(a0, W1, acc);
  acc = MFMA16(a1, W0, acc);
  acc = MFMA16(a0, W2, acc);
  acc = MFMA16(a1, W1, acc);
  acc = MFMA16(a2, W0, acc);
}

struct AFrag {
  bf16x8 a0, a1, a2;
};

// on-the-fly 3-plane split of fp32 input x (plain cached loads)
__device__ __forceinline__ AFrag ldAx(const float* base) {
  AFrag f;
#pragma unroll
  for (int e = 0; e < 8; ++e) {
    float xv = base[e];
    short s0 = bfs(xv);
    float f0 = bff(s0);
    float r1 = xv - f0;
    short s1 = bfs(r1);
    float f1 = bff(s1);
    short s2 = bfs(r1 - f1);
    f.a0[e] = s0;
    f.a1[e] = s1;
    f.a2[e] = s2;
  }
  return f;
}
__device__ __forceinline__ void mac6A(f32x4& acc, const AFrag& A, const bf16x8& W0,
                                      const bf16x8& W1, const bf16x8& W2) {
  mac6(acc, A.a0, A.a1, A.a2, W0, W1, W2);
}

// LDS weight slab read, XOR-swizzled
__device__ __forceinline__ bf16x8 ldW(int slab, int K2, int r, int kb) {
  extern __shared__ char smem[];
  return *(const bf16x8*)(smem + slab + ((r * K2 + kb) ^ ((r & 7) << 4)));
}

// stage one 16-row x K plane slab global->LDS with the same swizzle (once)
__device__ __forceinline__ void stage(int slabBase, const short* src, int K) {
  extern __shared__ char smem[];
  const int kc8 = K / 8;
  const int chunks = 16 * kc8;
  for (int c = threadIdx.x; c < chunks; c += blockDim.x) {
    const int row = c / kc8, kc = c % kc8;
    bf16x8 v = *(const bf16x8*)(src + row * K + kc * 8);
    *(bf16x8*)(smem + slabBase + ((row * (2 * K) + kc * 16) ^ ((row & 7) << 4))) = v;
  }
}

#define BC(x) __builtin_bit_cast(bf16x8, x)

// ---- pipelined GEMV slab units (K=512, 16 ks). A: 3-plane cached global. ----
// Full-slab batch: 48 loads in flight, one drain.
__device__ __forceinline__ void unit_h1(f32x4& acc, const short* aRow, int s0, int s1,
                                        int s2, int r, int g) {
  i32x4 A0[16], A1[16], A2[16];
#pragma unroll
  for (int ks = 0; ks < 16; ++ks) {
    A0[ks] = ldg16(aRow + ks * 32);
    A1[ks] = ldg16(aRow + ks * 32 + APLANE);
    A2[ks] = ldg16(aRow + ks * 32 + 2 * APLANE);
  }
  VMDRAIN();
#pragma unroll
  for (int ks = 0; ks < 16; ++ks) {
    const int kb = ks * 64 + g * 16;
    mac6(acc, BC(A0[ks]), BC(A1[ks]), BC(A2[ks]), ldW(s0, 1024, r, kb),
         ldW(s1, 1024, r, kb), ldW(s2, 1024, r, kb));
  }
}

__device__ __forceinline__ void unit_h2_lds(f32x4& acc0, f32x4& acc1, const short* aRow,
                                            int sa0, int sa1, int sa2, int sb0, int sb1,
                                            int sb2, int r, int g) {
  i32x4 A0[16], A1[16], A2[16];
#pragma unroll
  for (int ks = 0; ks < 16; ++ks) {
    A0[ks] = ldg16(aRow + ks * 32);
    A1[ks] = ldg16(aRow + ks * 32 + APLANE);
    A2[ks] = ldg16(aRow + ks * 32 + 2 * APLANE);
  }
  VMDRAIN();
#pragma unroll
  for (int ks = 0; ks < 16; ++ks) {
    const int kb = ks * 64 + g * 16;
    mac6(acc0, BC(A0[ks]), BC(A1[ks]), BC(A2[ks]), ldW(sa0, 1024, r, kb),
         ldW(sa1, 1024, r, kb), ldW(sa2, 1024, r, kb));
    mac6(acc1, BC(A0[ks]), BC(A1[ks]), BC(A2[ks]), ldW(sb0, 1024, r, kb),
         ldW(sb1, 1024, r, kb), ldW(sb2, 1024, r, kb));
  }
}

// gate unit with plane-2 weights streamed from global (cached): 8-ks batches (40 loads)
__device__ __forceinline__ void unit_h2_gw2(f32x4& acc0, f32x4& acc1, const short* aRow,
                                            int sa0, int sa1, const short* w2a, int sb0,
                                            int sb1, const short* w2b, int r, int g) {
#pragma unroll
  for (int b = 0; b < 2; ++b) {
    i32x4 A0[8], A1[8], A2[8], Wa[8], Wb2[8];
    const short* pp = aRow + b * 256;
#pragma unroll
    for (int ks = 0; ks < 8; ++ks) {
      A0[ks] = ldg16(pp + ks * 32);
      A1[ks] = ldg16(pp + ks * 32 + APLANE);
      A2[ks] = ldg16(pp + ks * 32 + 2 * APLANE);
      Wa[ks] = ldg16(w2a + b * 256 + ks * 32);
      Wb2[ks] = ldg16(w2b + b * 256 + ks * 32);
    }
    VMDRAIN();
#pragma unroll
    for (int ks = 0; ks < 8; ++ks) {
      const int kb = (b * 8 + ks) * 64 + g * 16;
      mac6(acc0, BC(A0[ks]), BC(A1[ks]), BC(A2[ks]), ldW(sa0, 1024, r, kb),
           ldW(sa1, 1024, r, kb), BC(Wa[ks]));
      mac6(acc1, BC(A0[ks]), BC(A1[ks]), BC(A2[ks]), ldW(sb0, 1024, r, kb),
           ldW(sb1, 1024, r, kb), BC(Wb2[ks]));
    }
  }
}

// ---- grid barrier: monotonic grouped relaxed atomics + per-wave acquire-inv ----
// bar layout (uints): [grp*32] group counters, [256] master, [288] gen
__device__ __forceinline__ void gbar(unsigned int* bar, unsigned int t, int grp) {
  asm volatile("s_waitcnt vmcnt(0) lgkmcnt(0)" ::: "memory");  // release: sc1 drained
  __syncthreads();
  if (threadIdx.x == 0) {
    unsigned int a = __hip_atomic_fetch_add(&bar[grp * 32], 1u, __ATOMIC_RELAXED,
                                            __HIP_MEMORY_SCOPE_AGENT);
    if (a == t * GSZ - 1) {
      unsigned int m = __hip_atomic_fetch_add(&bar[256], 1u, __ATOMIC_RELAXED,
                                              __HIP_MEMORY_SCOPE_AGENT);
      if (m == t * NGRP - 1)
        __hip_atomic_store(&bar[288], t, __ATOMIC_RELAXED, __HIP_MEMORY_SCOPE_AGENT);
    }
    while (__hip_atomic_load(&bar[288], __ATOMIC_RELAXED, __HIP_MEMORY_SCOPE_AGENT) < t)
      __builtin_amdgcn_s_sleep(1);
  }
  __syncthreads();
  // acquire: drop stale clean L1/L2 copies (non-destructive to dirty lines)
  asm volatile("buffer_inv sc1" ::: "memory");
  __builtin_amdgcn_sched_barrier(0);
}

struct PArgs {
  const float* x;
  const short* Wb;
  short* h0s;
  short* h1s;
  short* xn0;
  short* hn0;
  short* ch0;
  short* xn1;
  short* hn1;
  short* ch1;
  short* o0;
  short* o1;
  const float* bhi0;
  const float* bcho0;
  const float* bhi1;
  const float* bcho1;
  float* out;
  unsigned int* bar;
};

// Block map: 0-31 L1-gate | 32-63 L0-gate | 64-79 L0 xn/hn | 80-111 L1 xn/hn
//            112-143 B-L0 | 144-175 B-L1 | 176-207 C-L0 | 208-239 C-L1
__global__ __launch_bounds__(512, 2) void eltm_persist(PArgs p) {
  const int bid = blockIdx.x;
  const int lane = threadIdx.x & 63;
  const int w = threadIdx.x >> 6;
  const int r = lane & 15;
  const int g = lane >> 4;
  const int grp = bid & 7;
  const f32x4 z = {0.f, 0.f, 0.f, 0.f};

  // ---------------- one-time LDS weight staging ----------------
  if (bid < 32) {
    const int j0 = bid * 16;
    stage(0, p.Wb + OFF1_XI + j0 * 512, 512);
    stage(16384, p.Wb + OFF1_XI + WPLANE + j0 * 512, 512);
    stage(32768, p.Wb + OFF1_HI + j0 * 512, 512);
    stage(49152, p.Wb + OFF1_HI + WPLANE + j0 * 512, 512);
    stage(65536, p.Wb + OFF1_XI + (512 + j0) * 512, 512);
    stage(81920, p.Wb + OFF1_XI + WPLANE + (512 + j0) * 512, 512);
    stage(98304, p.Wb + OFF1_HI + (512 + j0) * 512, 512);
    stage(114688, p.Wb + OFF1_HI + WPLANE + (512 + j0) * 512, 512);
  } else if (bid < 64) {
    const int j0 = (bid - 32) * 16;
    for (int pl = 0; pl < 3; ++pl) {
      stage(pl * 4096, p.Wb + OFF0_XI + pl * WPLANE + j0 * 128, 128);
      stage(12288 + pl * 4096, p.Wb + OFF0_XI + pl * WPLANE + (512 + j0) * 128, 128);
      stage(24576 + pl * 16384, p.Wb + OFF0_HI + pl * WPLANE + j0 * 512, 512);
      stage(73728 + pl * 16384, p.Wb + OFF0_HI + pl * WPLANE + (512 + j0) * 512, 512);
    }
  } else if (bid < 80) {
    const int j0 = (bid - 64) * 32;
    for (int c = 0; c < 2; ++c) {
      const int base = c * 61440;
      for (int pl = 0; pl < 3; ++pl) {
        stage(base + pl * 4096, p.Wb + OFF0_OX + pl * WPLANE + (j0 + c * 16) * 128, 128);
        stage(base + 12288 + pl * 16384,
              p.Wb + OFF0_OH + pl * WPLANE + (j0 + c * 16) * 512, 512);
      }
    }
  } else if (bid < 112) {
    const int j0 = (bid - 80) * 16;
    for (int pl = 0; pl < 3; ++pl) {
      stage(pl * 16384, p.Wb + OFF1_OX + pl * WPLANE + j0 * 512, 512);
      stage(49152 + pl * 16384, p.Wb + OFF1_OH + pl * WPLANE + j0 * 512, 512);
    }
  } else if (bid < 176) {
    const int L = bid >= 144;
    const int j0 = (bid - (L ? 144 : 112)) * 16;
    const int oio = L ? OFF1_IO : OFF0_IO;
    const int oho = L ? OFF1_HO : OFF0_HO;
    const int och = L ? OFF1_CHO : OFF0_CHO;
    for (int pl = 0; pl < 3; ++pl) {
      stage(pl * 16384, p.Wb + oio + pl * WPLANE + j0 * 512, 512);
      stage(49152 + pl * 16384, p.Wb + oho + pl * WPLANE + j0 * 512, 512);
      stage(98304 + pl * 16384, p.Wb + och + pl * WPLANE + j0 * 512, 512);
    }
  } else {
    const int L = bid >= 208;
    const int j0 = (bid - (L ? 208 : 176)) * 16;
    const int oa = L ? OFF1_A : OFF0_A;
    const int ob = L ? OFF1_B : OFF0_B;
    for (int pl = 0; pl < 3; ++pl) {
      stage(pl * 16384, p.Wb + oa + pl * WPLANE + j0 * 512, 512);
      stage(49152 + pl * 16384, p.Wb + ob + pl * WPLANE + j0 * 512, 512);
    }
  }
  __syncthreads();

  unsigned int bt = 0;

  // ---------------- recurrence ----------------
  for (int i = 0; i <= S_; ++i) {
    const int do0 = i < S_;
    const int do1 = i >= 1;
    const int m0 = w * 16;
    // ============ phase A ============
    if (bid < 32) {
      if (do1) {  // L1 gates -> ch1 (step i-1)
        const int j0 = bid * 16;
        const int n = j0 + r;
        const float bi = p.bhi1[n], bh = p.bhi1[512 + n];
        f32x4 ig = z, hg = z;
        unit_h2_gw2(ig, hg, p.h0s + (m0 + r) * H_ + g * 8, 0, 16384,
                    p.Wb + OFF1_XI + 2 * WPLANE + (j0 + r) * 512 + g * 8, 65536, 81920,
                    p.Wb + OFF1_XI + 2 * WPLANE + (512 + j0 + r) * 512 + g * 8, r, g);
        unit_h2_gw2(ig, hg, p.h1s + (m0 + r) * H_ + g * 8, 32768, 49152,
                    p.Wb + OFF1_HI + 2 * WPLANE + (j0 + r) * 512 + g * 8, 98304, 114688,
                    p.Wb + OFF1_HI + 2 * WPLANE + (512 + j0 + r) * 512 + g * 8, r, g);
#pragma unroll
        for (int e = 0; e < 4; ++e)
          st3g(p.ch1, (m0 + g * 4 + e) * H_ + n, sigf(ig[e] + bi) * tanhf(hg[e] + bh));
      }
    } else if (bid < 64) {
      if (do0) {  // L0 gates -> ch0 (step i)
        const int j0 = (bid - 32) * 16;
        const int n = j0 + r;
        const float bi = p.bhi0[n], bh = p.bhi0[512 + n];
        f32x4 ig = z, hg = z;
        const float* xr = p.x + (size_t)i * B_ * D_ + (m0 + r) * D_ + g * 8;
#pragma unroll
        for (int ks = 0; ks < 4; ++ks) {
          AFrag A = ldAx(xr + ks * 32);
          const int kb = ks * 64 + g * 16;
          mac6A(ig, A, ldW(0, 256, r, kb), ldW(4096, 256, r, kb), ldW(8192, 256, r, kb));
          mac6A(hg, A, ldW(12288, 256, r, kb), ldW(16384, 256, r, kb),
                ldW(20480, 256, r, kb));
        }
        unit_h2_lds(ig, hg, p.h0s + (m0 + r) * H_ + g * 8, 24576, 40960, 57344, 73728,
                    90112, 106496, r, g);
#pragma unroll
        for (int e = 0; e < 4; ++e)
          st3g(p.ch0, (m0 + g * 4 + e) * H_ + n, sigf(ig[e] + bi) * tanhf(hg[e] + bh));
      }
    } else if (bid < 80) {
      if (do0) {  // L0 xn,hn (step i)
        const int j0 = (bid - 64) * 32;
#pragma unroll
        for (int c = 0; c < 2; ++c) {
          const int base = c * 61440;
          const int n = j0 + c * 16 + r;
          f32x4 ax = z;
          const float* xr = p.x + (size_t)i * B_ * D_ + (m0 + r) * D_ + g * 8;
#pragma unroll
          for (int ks = 0; ks < 4; ++ks) {
            AFrag A = ldAx(xr + ks * 32);
            const int kb = ks * 64 + g * 16;
            mac6A(ax, A, ldW(base, 256, r, kb), ldW(base + 4096, 256, r, kb),
                  ldW(base + 8192, 256, r, kb));
          }
#pragma unroll
          for (int e = 0; e < 4; ++e)
            st3g(p.xn0, (m0 + g * 4 + e) * H_ + n, tanhf(ax[e]));
          f32x4 ah = z;
          unit_h1(ah, p.h0s + (m0 + r) * H_ + g * 8, base + 12288, base + 28672,
                  base + 45056, r, g);
#pragma unroll
          for (int e = 0; e < 4; ++e)
            st3g(p.hn0, (m0 + g * 4 + e) * H_ + n, tanhf(ah[e]));
        }
      }
    } else if (bid < 112) {
      if (do1) {  // L1 xn,hn (step i-1)
        const int j0 = (bid - 80) * 16;
        const int n = j0 + r;
        f32x4 ax = z;
        unit_h1(ax, p.h0s + (m0 + r) * H_ + g * 8, 0, 16384, 32768, r, g);
#pragma unroll
        for (int e = 0; e < 4; ++e)
          st3g(p.xn1, (m0 + g * 4 + e) * H_ + n, tanhf(ax[e]));
        f32x4 ah = z;
        unit_h1(ah, p.h1s + (m0 + r) * H_ + g * 8, 49152, 65536, 81920, r, g);
#pragma unroll
        for (int e = 0; e < 4; ++e)
          st3g(p.hn1, (m0 + g * 4 + e) * H_ + n, tanhf(ah[e]));
      }
    }
    ++bt;
    gbar(p.bar, bt, grp);

    // ============ phase B ============
    if (bid >= 112 && bid < 176) {
      const int L = bid >= 144;
      if (L ? do1 : do0) {
        const int j0 = (bid - (L ? 144 : 112)) * 16;
        const int n = j0 + r;
        const float bc = (L ? p.bcho1 : p.bcho0)[n];
        const short* xn = L ? p.xn1 : p.xn0;
        const short* hn = L ? p.hn1 : p.hn0;
        const short* ch = L ? p.ch1 : p.ch0;
        f32x4 acc = z;
        unit_h1(acc, xn + (m0 + r) * H_ + g * 8, 0, 16384, 32768, r, g);
        unit_h1(acc, hn + (m0 + r) * H_ + g * 8, 49152, 65536, 81920, r, g);
        unit_h1(acc, ch + (m0 + r) * H_ + g * 8, 98304, 114688, 131072, r, g);
        short* o = L ? p.o1 : p.o0;
#pragma unroll
        for (int e = 0; e < 4; ++e)
          st3g(o, (m0 + g * 4 + e) * H_ + n, sigf(acc[e] + bc));
      }
    }
    ++bt;
    gbar(p.bar, bt, grp);

    // ============ phase C ============
    if (bid >= 176) {
      const int L = bid >= 208;
      if (L ? do1 : do0) {
        const int j0 = (bid - (L ? 208 : 176)) * 16;
        const int n = j0 + r;
        const short* o = L ? p.o1 : p.o0;
        f32x4 aA = z, aB = z;
        unit_h2_lds(aA, aB, o + (m0 + r) * H_ + g * 8, 0, 16384, 32768, 49152, 65536,
                    81920, r, g);
        const short* xn = L ? p.xn1 : p.xn0;
        const short* hn = L ? p.hn1 : p.hn0;
        const short* ch = L ? p.ch1 : p.ch0;
        short* hs = L ? p.h1s : p.h0s;
#pragma unroll
        for (int e = 0; e < 4; ++e) {
          const int idx = (m0 + g * 4 + e) * H_ + n;
          const float xv = ld3p(xn, idx);
          const float hv = ld3p(hn, idx);
          const float cv = ld3p(ch, idx);
          const float av = aA[e], bv = aB[e];
          const float hval = av * xv + bv * hv + (1.f - av - bv) * cv;
          st3g(hs, idx, hval);
          if (L) p.out[(size_t)(i - 1) * B_ * H_ + idx] = hval;
        }
      }
    }
    ++bt;
    gbar(p.bar, bt, grp);
  }
}

// ---------------- prologue: split fp32 weights into 3 bf16 planes ----------------
__global__ void wsplit(const float* __restrict__ src, short* __restrict__ dst, int n) {
  int i = blockIdx.x * 256 + threadIdx.x;
  if (i >= n) return;
  float v = src[i];
  short s0 = bfs(v);
  float f0 = bff(s0);
  float r1 = v - f0;
  short s1 = bfs(r1);
  float f1 = bff(s1);
  short s2 = bfs(r1 - f1);
  dst[i] = s0;
  dst[i + WPLANE] = s1;
  dst[i + 2 * WPLANE] = s2;
}

// ---------------- final: in-place sinrelu + LayerNorm over H on d_out ----------------
__global__ void eltm_kLN(float* __restrict__ out, const float* __restrict__ g,
                         const float* __restrict__ bta) {
  const int row = blockIdx.x * 4 + (threadIdx.x >> 6);
  const int lane = threadIdx.x & 63;
  float* r = out + (size_t)row * H_;
  float v[8];
  float s = 0.f, s2 = 0.f;
#pragma unroll
  for (int i = 0; i < 8; ++i) {
    float x = r[lane + i * 64];
    float sv = (x >= 0.f) ? (x + sinf(x)) : 0.f;
    v[i] = sv;
    s += sv;
    s2 += sv * sv;
  }
#pragma unroll
  for (int m = 1; m < 64; m <<= 1) {
    s += __shfl_xor(s, m);
    s2 += __shfl_xor(s2, m);
  }
  const float mean = s * (1.f / 512.f);
  const float var = s2 * (1.f / 512.f) - mean * mean;
  const float rstd = rsqrtf(var + 1e-5f);
#pragma unroll
  for (int i = 0; i < 8; ++i) {
    const int c = lane + i * 64;
    r[c] = (v[i] - mean) * rstd * g[c] + bta[c];
  }
}

extern "C" void kernel_launch(void* const* d_in, const int* in_sizes, int n_in,
                              void* d_out, int out_size, void* d_ws, size_t ws_size,
                              hipStream_t stream) {
  const float* x = (const float*)d_in[0];
#define W(i) ((const float*)d_in[i])
  short* Wb = (short*)d_ws;
  short* acts = (short*)((char*)d_ws + (size_t)3 * WPLANE * 2);
  const int ASZ = 3 * APLANE;
  short* h0s = acts;
  short* h1s = acts + ASZ;
  short* xn0 = acts + 2 * ASZ;
  short* hn0 = acts + 3 * ASZ;
  short* ch0 = acts + 4 * ASZ;
  short* xn1 = acts + 5 * ASZ;
  short* hn1 = acts + 6 * ASZ;
  short* ch1 = acts + 7 * ASZ;
  short* o0 = acts + 8 * ASZ;
  short* o1 = acts + 9 * ASZ;
  unsigned int* bar = (unsigned int*)(acts + 10 * ASZ);
  float* out = (float*)d_out;

  struct {
    int src;
    int off;
    int n;
  } wl[18] = {{1, OFF0_XI, 131072},   {2, OFF0_HI, 524288},  {4, OFF0_OX, 65536},
              {5, OFF0_OH, 262144},   {6, OFF0_IO, 262144},  {7, OFF0_HO, 262144},
              {8, OFF0_CHO, 262144},  {10, OFF0_A, 262144},  {11, OFF0_B, 262144},
              {12, OFF1_XI, 524288},  {13, OFF1_HI, 524288}, {15, OFF1_OX, 262144},
              {16, OFF1_OH, 262144},  {17, OFF1_IO, 262144}, {18, OFF1_HO, 262144},
              {19, OFF1_CHO, 262144}, {21, OFF1_A, 262144},  {22, OFF1_B, 262144}};
  for (int i = 0; i < 18; ++i)
    wsplit<<<(wl[i].n + 255) / 256, 256, 0, stream>>>(W(wl[i].src), Wb + wl[i].off,
                                                      wl[i].n);
  hipMemsetAsync(h0s, 0, (size_t)2 * ASZ * sizeof(short), stream);
  hipMemsetAsync(bar, 0, 4096, stream);

  hipFuncSetAttribute((const void*)eltm_persist,
                      hipFuncAttributeMaxDynamicSharedMemorySize, 147456);
  PArgs pa;
  pa.x = x;
  pa.Wb = Wb;
  pa.h0s = h0s;
  pa.h1s = h1s;
  pa.xn0 = xn0;
  pa.hn0 = hn0;
  pa.ch0 = ch0;
  pa.xn1 = xn1;
  pa.hn1 = hn1;
  pa.ch1 = ch1;
  pa.o0 = o0;
  pa.o1 = o1;
  pa.bhi0 = W(3);
  pa.bcho0 = W(9);
  pa.bhi1 = W(14);
  pa.bcho1 = W(20);
  pa.out = out;
  pa.bar = bar;
  eltm_persist<<<NB_, 512, 147456, stream>>>(pa);

  eltm_kLN<<<16384, 256, 0, stream>>>(out, W(23), W(24));
#undef W
}

// Round 6
// 31348.358 us; speedup vs baseline: 3.4241x; 3.4241x over previous
//
#include <hip/hip_runtime.h>
#include <hip/hip_bf16.h>

#define S_ 512
#define B_ 128
#define D_ 128
#define H_ 512
#define NB_ 256

// ---- packed weight layout (shorts) ----
#define PK_SA 239616
#define PK_B  7667712
#define PK_BS 147456
#define PK_C  12386304
#define PK_CS 98304
#define PK_TOT 15532032
#define APLANE 65536
#define ASZ    196608   // 3*APLANE

typedef short bf16x8 __attribute__((ext_vector_type(8)));
typedef int i32x4 __attribute__((ext_vector_type(4)));
typedef float f32x4 __attribute__((ext_vector_type(4)));

__device__ __forceinline__ float sigf(float x) { return 1.0f / (1.0f + expf(-x)); }
__device__ __forceinline__ short bfs(float v) {
  __hip_bfloat16 h = __float2bfloat16(v);
  return __builtin_bit_cast(short, h);
}
__device__ __forceinline__ float bff(short s) {
  __hip_bfloat16 h = __builtin_bit_cast(__hip_bfloat16, s);
  return __bfloat162float(h);
}

// plain cached 16B load
__device__ __forceinline__ i32x4 ldg(const short* p) {
  i32x4 o;
  asm volatile("global_load_dwordx4 %0, %1, off" : "=v"(o) : "v"(p));
  return o;
}
#define VMDRAIN()                                    \
  do {                                               \
    asm volatile("s_waitcnt vmcnt(0)" ::: "memory"); \
    __builtin_amdgcn_sched_barrier(0);               \
  } while (0)

// plain split-store / gather (3 bf16 planes); local-L2 visibility only
__device__ __forceinline__ void st3(short* buf, int idx, float v) {
  short s0 = bfs(v);
  float f0 = bff(s0);
  float r1 = v - f0;
  short s1 = bfs(r1);
  short s2 = bfs(r1 - bff(s1));
  buf[idx] = s0;
  buf[idx + APLANE] = s1;
  buf[idx + 2 * APLANE] = s2;
}
__device__ __forceinline__ float ld3p(const short* buf, int idx) {
  return bff(buf[idx]) + bff(buf[idx + APLANE]) + bff(buf[idx + 2 * APLANE]);
}

#define MFMA16(a, b, c) __builtin_amdgcn_mfma_f32_16x16x32_bf16(a, b, c, 0, 0, 0)
#define BC(x) __builtin_bit_cast(bf16x8, x)

__device__ __forceinline__ void mac6(f32x4& acc, const bf16x8& a0, const bf16x8& a1,
                                     const bf16x8& a2, const bf16x8& W0,
                                     const bf16x8& W1, const bf16x8& W2) {
  acc = MFMA16(a0, W0, acc);
  acc = MFMA16(a0, W1, acc);
  acc = MFMA16(a1, W0, acc);
  acc = MFMA16(a0, W2, acc);
  acc = MFMA16(a1, W1, acc);
  acc = MFMA16(a2, W0, acc);
}

struct AFrag {
  bf16x8 a0, a1, a2;
};
__device__ __forceinline__ AFrag ldAx(const float* base) {
  AFrag f;
#pragma unroll
  for (int e = 0; e < 8; ++e) {
    float xv = base[e];
    short s0 = bfs(xv);
    float f0 = bff(s0);
    float r1 = xv - f0;
    short s1 = bfs(r1);
    short s2 = bfs(r1 - bff(s1));
    f.a0[e] = s0;
    f.a1[e] = s1;
    f.a2[e] = s2;
  }
  return f;
}

// GEMV slab: A 3-plane activations (local L2), W packed fragment-ordered stream.
// Per kchunk c: W chunk = 3KB contiguous (3 planes x 1KB); lane offset r*32+g*8.
__device__ __forceinline__ void unitP(f32x4& acc, const short* aBase,
                                      const short* slab, int nks, int lo) {
  for (int c0 = 0; c0 < nks; c0 += 4) {
    i32x4 A0[4], A1[4], A2[4], W0[4], W1[4], W2[4];
#pragma unroll
    for (int u = 0; u < 4; ++u) {
      const short* wp = slab + (size_t)(c0 + u) * 1536 + lo;
      W0[u] = ldg(wp);
      W1[u] = ldg(wp + 512);
      W2[u] = ldg(wp + 1024);
      const short* ap = aBase + (c0 + u) * 32;
      A0[u] = ldg(ap);
      A1[u] = ldg(ap + APLANE);
      A2[u] = ldg(ap + 2 * APLANE);
    }
    VMDRAIN();
#pragma unroll
    for (int u = 0; u < 4; ++u)
      mac6(acc, BC(A0[u]), BC(A1[u]), BC(A2[u]), BC(W0[u]), BC(W1[u]), BC(W2[u]));
  }
}

// x-part (4 kchunks of fp32 x, split on the fly)
__device__ __forceinline__ void unitPx(f32x4& acc, const float* xRow,
                                       const short* slab, int lo) {
  i32x4 W0[4], W1[4], W2[4];
  AFrag A[4];
#pragma unroll
  for (int u = 0; u < 4; ++u) {
    const short* wp = slab + (size_t)u * 1536 + lo;
    W0[u] = ldg(wp);
    W1[u] = ldg(wp + 512);
    W2[u] = ldg(wp + 1024);
    A[u] = ldAx(xRow + u * 32);
  }
  VMDRAIN();
#pragma unroll
  for (int u = 0; u < 4; ++u)
    mac6(acc, A[u].a0, A[u].a1, A[u].a2, BC(W0[u]), BC(W1[u]), BC(W2[u]));
}

// ---- atomics (agent scope, relaxed, monotonic) ----
__device__ __forceinline__ unsigned int afa(unsigned int* p) {
  return __hip_atomic_fetch_add(p, 1u, __ATOMIC_RELAXED, __HIP_MEMORY_SCOPE_AGENT);
}
__device__ __forceinline__ unsigned int ald(const unsigned int* p) {
  return __hip_atomic_load(p, __ATOMIC_RELAXED, __HIP_MEMORY_SCOPE_AGENT);
}

// XCD-local barrier: ctl[32+32*x]=arrivals, ctl[48+32*x]=generation (monotonic)
__device__ __forceinline__ void gbarX(unsigned int* ctl, int xcd, unsigned int bt,
                                      unsigned int m) {
  asm volatile("s_waitcnt vmcnt(0) lgkmcnt(0)" ::: "memory");
  __syncthreads();
  if (threadIdx.x == 0) {
    unsigned int o = afa(&ctl[32 + 32 * xcd]);
    if (o == m * bt - 1)
      afa(&ctl[48 + 32 * xcd]);
    else
      while (ald(&ctl[48 + 32 * xcd]) < bt) __builtin_amdgcn_s_sleep(2);
  }
  __syncthreads();
  asm volatile("buffer_inv sc0" ::: "memory");  // vL1-only invalidate (same-XCD L2 is truth)
  __builtin_amdgcn_sched_barrier(0);
}

struct PP {
  const float* x;
  const short* pw;
  short* h0s;
  short* h1s;
  short* xn0;
  short* hn0;
  short* ch0;
  short* xn1;
  short* hn1;
  short* ch1;
  short* o0;
  short* o1;
  const float* bhi0;
  const float* bcho0;
  const float* bhi1;
  const float* bcho1;
  float* out;
  unsigned int* ctl;
};

__global__ __launch_bounds__(512, 1) void eltm_p(PP p) {
  extern __shared__ char smem[];
  float* ldsF = (float*)smem;                 // phase scratch (8KB max)
  unsigned int* shI = (unsigned int*)(smem + 16384);
  const int tid = threadIdx.x;
  const int lane = tid & 63;
  const int w = tid >> 6;
  const int r = lane & 15;
  const int g = lane >> 4;
  const int lo = r * 32 + g * 8;
  const f32x4 z = {0.f, 0.f, 0.f, 0.f};

  unsigned int xcd;
  asm volatile("s_getreg_b32 %0, hwreg(HW_REG_XCC_ID)" : "=s"(xcd));
  xcd &= 7;

  // self-organize + grid start barrier (all NB_ co-resident: 1 block/CU via LDS)
  if (tid == 0) {
    shI[0] = afa(&p.ctl[xcd]);  // slot within XCD
    unsigned int o = afa(&p.ctl[8]);
    if (o == NB_ - 1) __hip_atomic_store(&p.ctl[9], 1u, __ATOMIC_RELAXED, __HIP_MEMORY_SCOPE_AGENT);
    while (ald(&p.ctl[9]) == 0) __builtin_amdgcn_s_sleep(2);
    shI[1] = ald(&p.ctl[xcd]);  // m = blocks on this XCD
  }
  __syncthreads();
  const int slot = shI[0];
  const unsigned int m = shI[1];
  asm volatile("buffer_inv sc0" ::: "memory");

  const int row0 = (int)xcd * 16;           // slice rows [row0, row0+16)
  const int aoff = (row0 + r) * H_ + g * 8; // A-fragment lane base (plane 0)
  static const int preW[8] = {0, 30720, 61440, 67584, 92160, 141312, 190464, 215040};

  unsigned int bt = 0;
  for (int i = 0; i <= S_; ++i) {
    const int do0 = i < S_;
    const int do1 = i >= 1;
    const float* xr = p.x + ((size_t)i * B_ + row0 + r) * D_ + g * 8;

    // ================= phase A =================
    for (int s = slot; s < 32; s += (int)m) {
      const short* slabA = p.pw + (size_t)s * PK_SA;
      const int n = s * 16 + r;
      f32x4 acc = z;
      switch (w) {
        case 0:
        case 1:
          if (do0) {
            const short* sl = slabA + preW[w];
            unitPx(acc, xr, sl, lo);
            unitP(acc, p.h0s + aoff, sl + 4 * 1536, 16, lo);
          }
          break;
        case 2:
          if (do0) {
            unitPx(acc, xr, slabA + preW[2], lo);
#pragma unroll
            for (int e = 0; e < 4; ++e)
              st3(p.xn0, (row0 + g * 4 + e) * H_ + n, tanhf(acc[e]));
          }
          break;
        case 3:
          if (do0) {
            unitP(acc, p.h0s + aoff, slabA + preW[3], 16, lo);
#pragma unroll
            for (int e = 0; e < 4; ++e)
              st3(p.hn0, (row0 + g * 4 + e) * H_ + n, tanhf(acc[e]));
          }
          break;
        case 4:
        case 5:
          if (do1) {
            const short* sl = slabA + preW[w];
            unitP(acc, p.h0s + aoff, sl, 16, lo);
            unitP(acc, p.h1s + aoff, sl + 16 * 1536, 16, lo);
          }
          break;
        case 6:
          if (do1) {
            unitP(acc, p.h0s + aoff, slabA + preW[6], 16, lo);
#pragma unroll
            for (int e = 0; e < 4; ++e)
              st3(p.xn1, (row0 + g * 4 + e) * H_ + n, tanhf(acc[e]));
          }
          break;
        default:
          if (do1) {
            unitP(acc, p.h1s + aoff, slabA + preW[7], 16, lo);
#pragma unroll
            for (int e = 0; e < 4; ++e)
              st3(p.hn1, (row0 + g * 4 + e) * H_ + n, tanhf(acc[e]));
          }
          break;
      }
      if ((w == 1 && do0) || (w == 5 && do1)) {
#pragma unroll
        for (int e = 0; e < 4; ++e)
          ldsF[(w == 5 ? 256 : 0) + (g * 4 + e) * 16 + r] = acc[e];
      }
      __syncthreads();
      if (w == 0 && do0) {
        const float bi = p.bhi0[n], bh = p.bhi0[512 + n];
#pragma unroll
        for (int e = 0; e < 4; ++e) {
          float hgv = ldsF[(g * 4 + e) * 16 + r];
          st3(p.ch0, (row0 + g * 4 + e) * H_ + n, sigf(acc[e] + bi) * tanhf(hgv + bh));
        }
      }
      if (w == 4 && do1) {
        const float bi = p.bhi1[n], bh = p.bhi1[512 + n];
#pragma unroll
        for (int e = 0; e < 4; ++e) {
          float hgv = ldsF[256 + (g * 4 + e) * 16 + r];
          st3(p.ch1, (row0 + g * 4 + e) * H_ + n, sigf(acc[e] + bi) * tanhf(hgv + bh));
        }
      }
      __syncthreads();
    }
    ++bt;
    gbarX(p.ctl, xcd, bt, m);

    // ================= phase B =================
    for (int s = slot; s < 32; s += (int)m) {
      const int L = w >> 2;
      const int t = w & 3;
      const int ok = L ? do1 : do0;
      const int n = s * 16 + r;
      f32x4 acc = z;
      if (ok) {
        const short* slab = p.pw + PK_B + (size_t)s * PK_BS + (size_t)L * 3 * 24576;
        const short* xn = L ? p.xn1 : p.xn0;
        const short* hn = L ? p.hn1 : p.hn0;
        const short* ch = L ? p.ch1 : p.ch0;
        if (t == 0)
          unitP(acc, xn + aoff, slab, 16, lo);
        else if (t == 1)
          unitP(acc, hn + aoff, slab + 24576, 16, lo);
        else if (t == 2)
          unitP(acc, ch + aoff, slab + 2 * 24576, 8, lo);
        else
          unitP(acc, ch + aoff + 256, slab + 2 * 24576 + 8 * 1536, 8, lo);
#pragma unroll
        for (int e = 0; e < 4; ++e) ldsF[w * 256 + (g * 4 + e) * 16 + r] = acc[e];
      }
      __syncthreads();
      if ((w == 0 && do0) || (w == 4 && do1)) {
        const float bc = (w == 4 ? p.bcho1 : p.bcho0)[n];
        short* o = w == 4 ? p.o1 : p.o0;
#pragma unroll
        for (int e = 0; e < 4; ++e) {
          const int q = (g * 4 + e) * 16 + r;
          float sum = ldsF[w * 256 + q] + ldsF[(w + 1) * 256 + q] +
                      ldsF[(w + 2) * 256 + q] + ldsF[(w + 3) * 256 + q];
          st3(o, (row0 + g * 4 + e) * H_ + n, sigf(sum + bc));
        }
      }
      __syncthreads();
    }
    ++bt;
    gbarX(p.ctl, xcd, bt, m);

    // ================= phase C =================
    for (int s = slot; s < 32; s += (int)m) {
      const int L = s & 1;
      const int ok = L ? do1 : do0;
      const int u = w >> 1;
      const int h = w & 1;
      f32x4 acc = z;
      if (ok) {
        const short* slab =
            p.pw + PK_C + (size_t)s * PK_CS + (size_t)u * 24576 + (size_t)h * 8 * 1536;
        const short* o = L ? p.o1 : p.o0;
        unitP(acc, o + aoff + h * 256, slab, 8, lo);
#pragma unroll
        for (int e = 0; e < 4; ++e) ldsF[w * 256 + (g * 4 + e) * 16 + r] = acc[e];
      }
      __syncthreads();
      if ((w == 0 || w == 4) && ok) {
        const int j = (w == 0) ? (s >> 1) : (16 + (s >> 1));
        const int ub = (w == 0) ? 0 : 4;
        const short* xn = L ? p.xn1 : p.xn0;
        const short* hn = L ? p.hn1 : p.hn0;
        const short* ch = L ? p.ch1 : p.ch0;
        short* hs = L ? p.h1s : p.h0s;
#pragma unroll
        for (int e = 0; e < 4; ++e) {
          const int q = (g * 4 + e) * 16 + r;
          const float av = ldsF[(ub + 0) * 256 + q] + ldsF[(ub + 1) * 256 + q];
          const float bv = ldsF[(ub + 2) * 256 + q] + ldsF[(ub + 3) * 256 + q];
          const int idx = (row0 + g * 4 + e) * H_ + j * 16 + r;
          const float hval = av * ld3p(xn, idx) + bv * ld3p(hn, idx) +
                             (1.f - av - bv) * ld3p(ch, idx);
          st3(hs, idx, hval);
          if (L) p.out[(size_t)(i - 1) * B_ * H_ + idx] = hval;
        }
      }
      __syncthreads();
    }
    ++bt;
    gbarX(p.ctl, xcd, bt, m);
  }
}

// ---------------- prologue: repack fp32 weights -> packed 3-plane fragment stream ----------------
struct WP18 {
  const float* m[18];
};
__global__ void repack(WP18 wp, short* pw) {
  const long long t8 = (long long)blockIdx.x * 256 + threadIdx.x;
  const long long id = t8 * 8;
  if (id >= (long long)PK_TOT) return;
  int mat, row, kb, p;
  if (id < (long long)PK_B) {
    int s = (int)(id / PK_SA), rem = (int)(id % PK_SA);
    const int pre[9] = {0, 30720, 61440, 67584, 92160, 141312, 190464, 215040, 239616};
    int w = 0;
    while (rem >= pre[w + 1]) ++w;
    int off = rem - pre[w];
    int c = off / 1536, r2 = off % 1536;
    p = r2 / 512;
    int q2 = r2 % 512, rr = q2 / 32, gg = (q2 & 31) >> 3;
    int kin = c * 32 + gg * 8;
    switch (w) {
      case 0:
      case 1:
        row = (w == 1 ? 512 : 0) + s * 16 + rr;
        if (kin < 128) { mat = 0; kb = kin; } else { mat = 1; kb = kin - 128; }
        break;
      case 2: mat = 2; row = s * 16 + rr; kb = kin; break;
      case 3: mat = 3; row = s * 16 + rr; kb = kin; break;
      case 4:
      case 5:
        row = (w == 5 ? 512 : 0) + s * 16 + rr;
        if (kin < 512) { mat = 9; kb = kin; } else { mat = 10; kb = kin - 512; }
        break;
      case 6: mat = 11; row = s * 16 + rr; kb = kin; break;
      default: mat = 12; row = s * 16 + rr; kb = kin; break;
    }
  } else if (id < (long long)PK_C) {
    int rem = (int)(id - PK_B);
    int s = rem / PK_BS, r2 = rem % PK_BS;
    int t = r2 / 24576, off = r2 % 24576;
    int c = off / 1536, r3 = off % 1536;
    p = r3 / 512;
    int q2 = r3 % 512, rr = q2 / 32, gg = (q2 & 31) >> 3;
    const int mats[6] = {4, 5, 6, 13, 14, 15};
    mat = mats[t];
    row = s * 16 + rr;
    kb = c * 32 + gg * 8;
  } else {
    int rem = (int)(id - PK_C);
    int s = rem / PK_CS, r2 = rem % PK_CS;
    int u = r2 / 24576, off = r2 % 24576;
    int c = off / 1536, r3 = off % 1536;
    p = r3 / 512;
    int q2 = r3 % 512, rr = q2 / 32, gg = (q2 & 31) >> 3;
    int L = s & 1, j = (u < 2) ? (s >> 1) : (16 + (s >> 1));
    mat = (L ? 16 : 7) + (u & 1);
    row = j * 16 + rr;
    kb = c * 32 + gg * 8;
  }
  const int KS = (mat == 0 || mat == 2) ? 128 : 512;
  const float* src = wp.m[mat] + (long long)row * KS + kb;
  bf16x8 o8;
#pragma unroll
  for (int e = 0; e < 8; ++e) {
    float v = src[e];
    short s0 = bfs(v);
    float f0 = bff(s0);
    float r1 = v - f0;
    short s1 = bfs(r1);
    short s2 = bfs(r1 - bff(s1));
    o8[e] = (p == 0) ? s0 : ((p == 1) ? s1 : s2);
  }
  *(bf16x8*)(pw + id) = o8;
}

// ---------------- final: in-place sinrelu + LayerNorm over H on d_out ----------------
__global__ void eltm_kLN(float* __restrict__ out, const float* __restrict__ g,
                         const float* __restrict__ bta) {
  const int row = blockIdx.x * 4 + (threadIdx.x >> 6);
  const int lane = threadIdx.x & 63;
  float* r = out + (size_t)row * H_;
  float v[8];
  float s = 0.f, s2 = 0.f;
#pragma unroll
  for (int i = 0; i < 8; ++i) {
    float x = r[lane + i * 64];
    float sv = (x >= 0.f) ? (x + sinf(x)) : 0.f;
    v[i] = sv;
    s += sv;
    s2 += sv * sv;
  }
#pragma unroll
  for (int m = 1; m < 64; m <<= 1) {
    s += __shfl_xor(s, m);
    s2 += __shfl_xor(s2, m);
  }
  const float mean = s * (1.f / 512.f);
  const float var = s2 * (1.f / 512.f) - mean * mean;
  const float rstd = rsqrtf(var + 1e-5f);
#pragma unroll
  for (int i = 0; i < 8; ++i) {
    const int c = lane + i * 64;
    r[c] = (v[i] - mean) * rstd * g[c] + bta[c];
  }
}

extern "C" void kernel_launch(void* const* d_in, const int* in_sizes, int n_in,
                              void* d_out, int out_size, void* d_ws, size_t ws_size,
                              hipStream_t stream) {
#define W(i) ((const float*)d_in[i])
  short* pw = (short*)d_ws;
  short* acts = pw + (size_t)PK_TOT;
  short* h0s = acts;
  short* h1s = acts + ASZ;
  short* xn0 = acts + 2 * ASZ;
  short* hn0 = acts + 3 * ASZ;
  short* ch0 = acts + 4 * ASZ;
  short* xn1 = acts + 5 * ASZ;
  short* hn1 = acts + 6 * ASZ;
  short* ch1 = acts + 7 * ASZ;
  short* o0 = acts + 8 * ASZ;
  short* o1 = acts + 9 * ASZ;
  unsigned int* ctl = (unsigned int*)(acts + 10 * (size_t)ASZ);
  float* out = (float*)d_out;

  WP18 wps;
  const int srcIdx[18] = {1, 2, 4, 5, 6, 7, 8, 10, 11, 12, 13, 15, 16, 17, 18, 19, 21, 22};
  for (int i = 0; i < 18; ++i) wps.m[i] = W(srcIdx[i]);

  repack<<<PK_TOT / 8 / 256, 256, 0, stream>>>(wps, pw);
  hipMemsetAsync(h0s, 0, (size_t)2 * ASZ * sizeof(short), stream);
  hipMemsetAsync(ctl, 0, 2048, stream);

  hipFuncSetAttribute((const void*)eltm_p, hipFuncAttributeMaxDynamicSharedMemorySize,
                      98304);
  PP pa;
  pa.x = (const float*)d_in[0];
  pa.pw = pw;
  pa.h0s = h0s;
  pa.h1s = h1s;
  pa.xn0 = xn0;
  pa.hn0 = hn0;
  pa.ch0 = ch0;
  pa.xn1 = xn1;
  pa.hn1 = hn1;
  pa.ch1 = ch1;
  pa.o0 = o0;
  pa.o1 = o1;
  pa.bhi0 = W(3);
  pa.bcho0 = W(9);
  pa.bhi1 = W(14);
  pa.bcho1 = W(20);
  pa.out = out;
  pa.ctl = ctl;
  eltm_p<<<NB_, 512, 98304, stream>>>(pa);

  eltm_kLN<<<16384, 256, 0, stream>>>(out, W(23), W(24));
#undef W
}

// Round 7
// 20946.999 us; speedup vs baseline: 5.1243x; 1.4966x over previous
//
#include <hip/hip_runtime.h>
#include <hip/hip_bf16.h>

#define S_ 512
#define B_ 128
#define D_ 128
#define H_ 512
#define NB_ 256

// ---- packed f16 2-plane weight layout (shorts) ----
#define PK_SA 159744
#define PK_B  5111808
#define PK_BS 98304
#define PK_C  8257536
#define PK_CS 65536
#define PK_TOT 10354688
#define APLANE 65536
#define ASZ    131072   // 2*APLANE

#define SC1 4.8828125e-4f          // 2^-11
#define SC2 2.384185791015625e-7f  // 2^-22

typedef short bf16x8 __attribute__((ext_vector_type(8)));  // generic 16B short container
typedef _Float16 f16x8 __attribute__((ext_vector_type(8)));
typedef int i32x4 __attribute__((ext_vector_type(4)));
typedef float f32x4 __attribute__((ext_vector_type(4)));

__device__ __forceinline__ float sigf(float x) { return 1.0f / (1.0f + expf(-x)); }

// plain cached 16B load
__device__ __forceinline__ i32x4 ldg(const short* p) {
  i32x4 o;
  asm volatile("global_load_dwordx4 %0, %1, off" : "=v"(o) : "v"(p));
  return o;
}
#define VMDRAIN()                                    \
  do {                                               \
    asm volatile("s_waitcnt vmcnt(0)" ::: "memory"); \
    __builtin_amdgcn_sched_barrier(0);               \
  } while (0)

// f16 2-plane split-store / gather (local-XCD L2 visibility only)
__device__ __forceinline__ void st2(short* buf, int idx, float v) {
  _Float16 h0 = (_Float16)v;
  float r1 = (v - (float)h0) * 2048.0f;
  _Float16 h1 = (_Float16)r1;
  buf[idx] = __builtin_bit_cast(short, h0);
  buf[idx + APLANE] = __builtin_bit_cast(short, h1);
}
__device__ __forceinline__ float ld2p(const short* buf, int idx) {
  float a = (float)__builtin_bit_cast(_Float16, buf[idx]);
  float b = (float)__builtin_bit_cast(_Float16, buf[idx + APLANE]);
  return a + b * SC1;
}

#define MFMAH(a, b, c) __builtin_amdgcn_mfma_f32_16x16x32_f16(a, b, c, 0, 0, 0)
#define BC16(x) __builtin_bit_cast(f16x8, x)

__device__ __forceinline__ void mac4(f32x4& c0, f32x4& c1, f32x4& c2, const f16x8& a0,
                                     const f16x8& a1, const f16x8& w0, const f16x8& w1) {
  c0 = MFMAH(a0, w0, c0);
  c1 = MFMAH(a0, w1, c1);
  c1 = MFMAH(a1, w0, c1);
  c2 = MFMAH(a1, w1, c2);
}
__device__ __forceinline__ f32x4 fin3(const f32x4& c0, const f32x4& c1,
                                      const f32x4& c2) {
  f32x4 o;
#pragma unroll
  for (int e = 0; e < 4; ++e) o[e] = c0[e] + SC1 * c1[e] + SC2 * c2[e];
  return o;
}

// GEMV slab: A 2-plane f16 activations (local L2), W packed fragment-ordered stream.
// Per kchunk: W chunk = 2KB contiguous (2 planes x 1KB); lane offset lo = r*32+g*8.
__device__ __forceinline__ void unitP(f32x4& c0, f32x4& c1, f32x4& c2,
                                      const short* aBase, const short* slab, int nks,
                                      int lo) {
  for (int q = 0; q < nks; q += 4) {
    i32x4 A0[4], A1[4], W0[4], W1[4];
#pragma unroll
    for (int u = 0; u < 4; ++u) {
      const short* wp = slab + (size_t)(q + u) * 1024 + lo;
      W0[u] = ldg(wp);
      W1[u] = ldg(wp + 512);
      const short* ap = aBase + (q + u) * 32;
      A0[u] = ldg(ap);
      A1[u] = ldg(ap + APLANE);
    }
    VMDRAIN();
#pragma unroll
    for (int u = 0; u < 4; ++u)
      mac4(c0, c1, c2, BC16(A0[u]), BC16(A1[u]), BC16(W0[u]), BC16(W1[u]));
  }
}

// x-part (4 kchunks of fp32 x, split on the fly)
__device__ __forceinline__ void unitPx(f32x4& c0, f32x4& c1, f32x4& c2,
                                       const float* xRow, const short* slab, int lo) {
  i32x4 W0[4], W1[4];
  f16x8 A0[4], A1[4];
#pragma unroll
  for (int u = 0; u < 4; ++u) {
    const short* wp = slab + (size_t)u * 1024 + lo;
    W0[u] = ldg(wp);
    W1[u] = ldg(wp + 512);
#pragma unroll
    for (int e = 0; e < 8; ++e) {
      float v = xRow[u * 32 + e];
      _Float16 h0 = (_Float16)v;
      A0[u][e] = h0;
      A1[u][e] = (_Float16)((v - (float)h0) * 2048.0f);
    }
  }
  VMDRAIN();
#pragma unroll
  for (int u = 0; u < 4; ++u) mac4(c0, c1, c2, A0[u], A1[u], BC16(W0[u]), BC16(W1[u]));
}

// ---- atomics (agent scope, relaxed, monotonic) ----
__device__ __forceinline__ unsigned int afa(unsigned int* p) {
  return __hip_atomic_fetch_add(p, 1u, __ATOMIC_RELAXED, __HIP_MEMORY_SCOPE_AGENT);
}
__device__ __forceinline__ unsigned int ald(const unsigned int* p) {
  return __hip_atomic_load(p, __ATOMIC_RELAXED, __HIP_MEMORY_SCOPE_AGENT);
}

// XCD-local barrier: ctl[32+32*x]=arrivals, ctl[48+32*x]=generation (monotonic)
__device__ __forceinline__ void gbarX(unsigned int* ctl, int xcd, unsigned int bt,
                                      unsigned int m) {
  asm volatile("s_waitcnt vmcnt(0) lgkmcnt(0)" ::: "memory");
  __syncthreads();
  if (threadIdx.x == 0) {
    unsigned int o = afa(&ctl[32 + 32 * xcd]);
    if (o == m * bt - 1)
      afa(&ctl[48 + 32 * xcd]);
    else
      while (ald(&ctl[48 + 32 * xcd]) < bt) __builtin_amdgcn_s_sleep(2);
  }
  __syncthreads();
  asm volatile("buffer_inv sc0" ::: "memory");  // vL1-only invalidate (same-XCD L2 is truth)
  __builtin_amdgcn_sched_barrier(0);
}

struct PP {
  const float* x;
  const short* pw;
  short* h0s;
  short* h1s;
  short* xn0;
  short* hn0;
  short* ch0;
  short* xn1;
  short* hn1;
  short* ch1;
  short* o0;
  short* o1;
  const float* bhi0;
  const float* bcho0;
  const float* bhi1;
  const float* bcho1;
  float* out;
  unsigned int* ctl;
};

__global__ __launch_bounds__(512, 1) void eltm_p(PP p) {
  extern __shared__ char smem[];
  float* ldsF = (float*)smem;  // phase scratch (8KB max)
  unsigned int* shI = (unsigned int*)(smem + 16384);
  const int tid = threadIdx.x;
  const int lane = tid & 63;
  const int w = tid >> 6;
  const int r = lane & 15;
  const int g = lane >> 4;
  const int lo = r * 32 + g * 8;
  const f32x4 z = {0.f, 0.f, 0.f, 0.f};

  unsigned int xcd;
  asm volatile("s_getreg_b32 %0, hwreg(HW_REG_XCC_ID)" : "=s"(xcd));
  xcd &= 7;
  const int sgx = ((int)xcd) << 2;  // slab stagger offset per XCD

  // self-organize + grid start barrier (all NB_ co-resident: 1 block/CU via LDS)
  if (tid == 0) {
    shI[0] = afa(&p.ctl[xcd]);  // slot within XCD
    unsigned int o = afa(&p.ctl[8]);
    if (o == NB_ - 1)
      __hip_atomic_store(&p.ctl[9], 1u, __ATOMIC_RELAXED, __HIP_MEMORY_SCOPE_AGENT);
    while (ald(&p.ctl[9]) == 0) __builtin_amdgcn_s_sleep(2);
    shI[1] = ald(&p.ctl[xcd]);  // m = blocks on this XCD
  }
  __syncthreads();
  const int slot = shI[0];
  const unsigned int m = shI[1];
  asm volatile("buffer_inv sc0" ::: "memory");

  const int row0 = (int)xcd * 16;            // slice rows [row0, row0+16)
  const int aoff = (row0 + r) * H_ + g * 8;  // A-fragment lane base (plane 0)
  static const int preW[8] = {0, 20480, 40960, 45056, 61440, 94208, 126976, 143360};

  unsigned int bt = 0;
  for (int i = 0; i <= S_; ++i) {
    const int do0 = i < S_;
    const int do1 = i >= 1;
    const float* xr = p.x + ((size_t)i * B_ + row0 + r) * D_ + g * 8;

    // ================= phase A =================
    for (int t = slot; t < 32; t += (int)m) {
      const int s = (t + sgx) & 31;
      const short* slabA = p.pw + (size_t)s * PK_SA;
      const int n = s * 16 + r;
      f32x4 c0 = z, c1 = z, c2 = z;
      f32x4 fin = z;
      switch (w) {
        case 0:
        case 1:
          if (do0) {
            const short* sl = slabA + preW[w];
            unitPx(c0, c1, c2, xr, sl, lo);
            unitP(c0, c1, c2, p.h0s + aoff, sl + 4096, 16, lo);
            fin = fin3(c0, c1, c2);
          }
          break;
        case 2:
          if (do0) {
            unitPx(c0, c1, c2, xr, slabA + preW[2], lo);
            fin = fin3(c0, c1, c2);
#pragma unroll
            for (int e = 0; e < 4; ++e)
              st2(p.xn0, (row0 + g * 4 + e) * H_ + n, tanhf(fin[e]));
          }
          break;
        case 3:
          if (do0) {
            unitP(c0, c1, c2, p.h0s + aoff, slabA + preW[3], 16, lo);
            fin = fin3(c0, c1, c2);
#pragma unroll
            for (int e = 0; e < 4; ++e)
              st2(p.hn0, (row0 + g * 4 + e) * H_ + n, tanhf(fin[e]));
          }
          break;
        case 4:
        case 5:
          if (do1) {
            const short* sl = slabA + preW[w];
            unitP(c0, c1, c2, p.h0s + aoff, sl, 16, lo);
            unitP(c0, c1, c2, p.h1s + aoff, sl + 16384, 16, lo);
            fin = fin3(c0, c1, c2);
          }
          break;
        case 6:
          if (do1) {
            unitP(c0, c1, c2, p.h0s + aoff, slabA + preW[6], 16, lo);
            fin = fin3(c0, c1, c2);
#pragma unroll
            for (int e = 0; e < 4; ++e)
              st2(p.xn1, (row0 + g * 4 + e) * H_ + n, tanhf(fin[e]));
          }
          break;
        default:
          if (do1) {
            unitP(c0, c1, c2, p.h1s + aoff, slabA + preW[7], 16, lo);
            fin = fin3(c0, c1, c2);
#pragma unroll
            for (int e = 0; e < 4; ++e)
              st2(p.hn1, (row0 + g * 4 + e) * H_ + n, tanhf(fin[e]));
          }
          break;
      }
      if ((w == 1 && do0) || (w == 5 && do1)) {
#pragma unroll
        for (int e = 0; e < 4; ++e)
          ldsF[(w == 5 ? 256 : 0) + (g * 4 + e) * 16 + r] = fin[e];
      }
      __syncthreads();
      if (w == 0 && do0) {
        const float bi = p.bhi0[n], bh = p.bhi0[512 + n];
#pragma unroll
        for (int e = 0; e < 4; ++e) {
          float hgv = ldsF[(g * 4 + e) * 16 + r];
          st2(p.ch0, (row0 + g * 4 + e) * H_ + n, sigf(fin[e] + bi) * tanhf(hgv + bh));
        }
      }
      if (w == 4 && do1) {
        const float bi = p.bhi1[n], bh = p.bhi1[512 + n];
#pragma unroll
        for (int e = 0; e < 4; ++e) {
          float hgv = ldsF[256 + (g * 4 + e) * 16 + r];
          st2(p.ch1, (row0 + g * 4 + e) * H_ + n, sigf(fin[e] + bi) * tanhf(hgv + bh));
        }
      }
      __syncthreads();
    }
    ++bt;
    gbarX(p.ctl, xcd, bt, m);

    // ================= phase B =================
    for (int t = slot; t < 32; t += (int)m) {
      const int s = (t + sgx) & 31;
      const int L = w >> 2;
      const int tt = w & 3;
      const int ok = L ? do1 : do0;
      const int n = s * 16 + r;
      if (ok) {
        f32x4 c0 = z, c1 = z, c2 = z;
        const short* slab = p.pw + PK_B + (size_t)s * PK_BS + (size_t)L * 49152;
        const short* xn = L ? p.xn1 : p.xn0;
        const short* hn = L ? p.hn1 : p.hn0;
        const short* ch = L ? p.ch1 : p.ch0;
        if (tt == 0)
          unitP(c0, c1, c2, xn + aoff, slab, 16, lo);
        else if (tt == 1)
          unitP(c0, c1, c2, hn + aoff, slab + 16384, 16, lo);
        else if (tt == 2)
          unitP(c0, c1, c2, ch + aoff, slab + 32768, 8, lo);
        else
          unitP(c0, c1, c2, ch + aoff + 256, slab + 40960, 8, lo);
        f32x4 fin = fin3(c0, c1, c2);
#pragma unroll
        for (int e = 0; e < 4; ++e) ldsF[w * 256 + (g * 4 + e) * 16 + r] = fin[e];
      }
      __syncthreads();
      if ((w == 0 && do0) || (w == 4 && do1)) {
        const float bc = (w == 4 ? p.bcho1 : p.bcho0)[n];
        short* o = w == 4 ? p.o1 : p.o0;
#pragma unroll
        for (int e = 0; e < 4; ++e) {
          const int q = (g * 4 + e) * 16 + r;
          float sum = ldsF[w * 256 + q] + ldsF[(w + 1) * 256 + q] +
                      ldsF[(w + 2) * 256 + q] + ldsF[(w + 3) * 256 + q];
          st2(o, (row0 + g * 4 + e) * H_ + n, sigf(sum + bc));
        }
      }
      __syncthreads();
    }
    ++bt;
    gbarX(p.ctl, xcd, bt, m);

    // ================= phase C =================
    for (int t = slot; t < 32; t += (int)m) {
      const int s = (t + sgx) & 31;
      const int L = s & 1;
      const int ok = L ? do1 : do0;
      const int u = w >> 1;
      const int h = w & 1;
      if (ok) {
        f32x4 c0 = z, c1 = z, c2 = z;
        const short* slab =
            p.pw + PK_C + (size_t)s * PK_CS + (size_t)u * 16384 + (size_t)h * 8192;
        const short* o = L ? p.o1 : p.o0;
        unitP(c0, c1, c2, o + aoff + h * 256, slab, 8, lo);
        f32x4 fin = fin3(c0, c1, c2);
#pragma unroll
        for (int e = 0; e < 4; ++e) ldsF[w * 256 + (g * 4 + e) * 16 + r] = fin[e];
      }
      __syncthreads();
      if ((w == 0 || w == 4) && ok) {
        const int j = (w == 0) ? (s >> 1) : (16 + (s >> 1));
        const int ub = (w == 0) ? 0 : 4;
        const short* xn = L ? p.xn1 : p.xn0;
        const short* hn = L ? p.hn1 : p.hn0;
        const short* ch = L ? p.ch1 : p.ch0;
        short* hs = L ? p.h1s : p.h0s;
#pragma unroll
        for (int e = 0; e < 4; ++e) {
          const int q = (g * 4 + e) * 16 + r;
          const float av = ldsF[(ub + 0) * 256 + q] + ldsF[(ub + 1) * 256 + q];
          const float bv = ldsF[(ub + 2) * 256 + q] + ldsF[(ub + 3) * 256 + q];
          const int idx = (row0 + g * 4 + e) * H_ + j * 16 + r;
          const float hval = av * ld2p(xn, idx) + bv * ld2p(hn, idx) +
                             (1.f - av - bv) * ld2p(ch, idx);
          st2(hs, idx, hval);
          if (L) p.out[(size_t)(i - 1) * B_ * H_ + idx] = hval;
        }
      }
      __syncthreads();
    }
    ++bt;
    gbarX(p.ctl, xcd, bt, m);
  }
}

// ---------------- prologue: repack fp32 weights -> packed f16 2-plane fragment stream ----------------
struct WP18 {
  const float* m[18];
};
__global__ void repack(WP18 wp, short* pw) {
  const long long t8 = (long long)blockIdx.x * 256 + threadIdx.x;
  const long long id = t8 * 8;
  if (id >= (long long)PK_TOT) return;
  int mat, row, kb, p;
  if (id < (long long)PK_B) {
    int s = (int)(id / PK_SA), rem = (int)(id % PK_SA);
    const int pre[9] = {0, 20480, 40960, 45056, 61440, 94208, 126976, 143360, 159744};
    int w = 0;
    while (rem >= pre[w + 1]) ++w;
    int off = rem - pre[w];
    int c = off >> 10, r2 = off & 1023;
    p = r2 >> 9;
    int q2 = r2 & 511, rr = q2 >> 5, gg = (q2 & 31) >> 3;
    int kin = c * 32 + gg * 8;
    switch (w) {
      case 0:
      case 1:
        row = (w == 1 ? 512 : 0) + s * 16 + rr;
        if (kin < 128) { mat = 0; kb = kin; } else { mat = 1; kb = kin - 128; }
        break;
      case 2: mat = 2; row = s * 16 + rr; kb = kin; break;
      case 3: mat = 3; row = s * 16 + rr; kb = kin; break;
      case 4:
      case 5:
        row = (w == 5 ? 512 : 0) + s * 16 + rr;
        if (kin < 512) { mat = 9; kb = kin; } else { mat = 10; kb = kin - 512; }
        break;
      case 6: mat = 11; row = s * 16 + rr; kb = kin; break;
      default: mat = 12; row = s * 16 + rr; kb = kin; break;
    }
  } else if (id < (long long)PK_C) {
    int rem = (int)(id - PK_B);
    int s = rem / PK_BS, r2 = rem % PK_BS;
    int tt = r2 / 16384, off = r2 % 16384;
    int c = off >> 10, r3 = off & 1023;
    p = r3 >> 9;
    int q2 = r3 & 511, rr = q2 >> 5, gg = (q2 & 31) >> 3;
    const int mats[6] = {4, 5, 6, 13, 14, 15};
    mat = mats[tt];
    row = s * 16 + rr;
    kb = c * 32 + gg * 8;
  } else {
    int rem = (int)(id - PK_C);
    int s = rem / PK_CS, r2 = rem % PK_CS;
    int u = r2 / 16384, off = r2 % 16384;
    int c = off >> 10, r3 = off & 1023;
    p = r3 >> 9;
    int q2 = r3 & 511, rr = q2 >> 5, gg = (q2 & 31) >> 3;
    int L = s & 1, j = (u < 2) ? (s >> 1) : (16 + (s >> 1));
    mat = (L ? 16 : 7) + (u & 1);
    row = j * 16 + rr;
    kb = c * 32 + gg * 8;
  }
  const int KS = (mat == 0 || mat == 2) ? 128 : 512;
  const float* src = wp.m[mat] + (long long)row * KS + kb;
  bf16x8 o8;
#pragma unroll
  for (int e = 0; e < 8; ++e) {
    float v = src[e];
    _Float16 h0 = (_Float16)v;
    short sv;
    if (p == 0) {
      sv = __builtin_bit_cast(short, h0);
    } else {
      _Float16 h1 = (_Float16)((v - (float)h0) * 2048.0f);
      sv = __builtin_bit_cast(short, h1);
    }
    o8[e] = sv;
  }
  *(bf16x8*)(pw + id) = o8;
}

// ---------------- final: in-place sinrelu + LayerNorm over H on d_out ----------------
__global__ void eltm_kLN(float* __restrict__ out, const float* __restrict__ g,
                         const float* __restrict__ bta) {
  const int row = blockIdx.x * 4 + (threadIdx.x >> 6);
  const int lane = threadIdx.x & 63;
  float* r = out + (size_t)row * H_;
  float v[8];
  float s = 0.f, s2 = 0.f;
#pragma unroll
  for (int i = 0; i < 8; ++i) {
    float x = r[lane + i * 64];
    float sv = (x >= 0.f) ? (x + sinf(x)) : 0.f;
    v[i] = sv;
    s += sv;
    s2 += sv * sv;
  }
#pragma unroll
  for (int m = 1; m < 64; m <<= 1) {
    s += __shfl_xor(s, m);
    s2 += __shfl_xor(s2, m);
  }
  const float mean = s * (1.f / 512.f);
  const float var = s2 * (1.f / 512.f) - mean * mean;
  const float rstd = rsqrtf(var + 1e-5f);
#pragma unroll
  for (int i = 0; i < 8; ++i) {
    const int c = lane + i * 64;
    r[c] = (v[i] - mean) * rstd * g[c] + bta[c];
  }
}

extern "C" void kernel_launch(void* const* d_in, const int* in_sizes, int n_in,
                              void* d_out, int out_size, void* d_ws, size_t ws_size,
                              hipStream_t stream) {
#define W(i) ((const float*)d_in[i])
  short* pw = (short*)d_ws;
  short* acts = pw + (size_t)PK_TOT;
  short* h0s = acts;
  short* h1s = acts + ASZ;
  short* xn0 = acts + 2 * ASZ;
  short* hn0 = acts + 3 * ASZ;
  short* ch0 = acts + 4 * ASZ;
  short* xn1 = acts + 5 * ASZ;
  short* hn1 = acts + 6 * ASZ;
  short* ch1 = acts + 7 * ASZ;
  short* o0 = acts + 8 * ASZ;
  short* o1 = acts + 9 * ASZ;
  unsigned int* ctl = (unsigned int*)(acts + 10 * (size_t)ASZ);
  float* out = (float*)d_out;

  WP18 wps;
  const int srcIdx[18] = {1, 2, 4, 5, 6, 7, 8, 10, 11, 12, 13, 15, 16, 17, 18, 19, 21, 22};
  for (int i = 0; i < 18; ++i) wps.m[i] = W(srcIdx[i]);

  repack<<<PK_TOT / 8 / 256, 256, 0, stream>>>(wps, pw);
  hipMemsetAsync(h0s, 0, (size_t)2 * ASZ * sizeof(short), stream);
  hipMemsetAsync(ctl, 0, 2048, stream);

  hipFuncSetAttribute((const void*)eltm_p, hipFuncAttributeMaxDynamicSharedMemorySize,
                      98304);
  PP pa;
  pa.x = (const float*)d_in[0];
  pa.pw = pw;
  pa.h0s = h0s;
  pa.h1s = h1s;
  pa.xn0 = xn0;
  pa.hn0 = hn0;
  pa.ch0 = ch0;
  pa.xn1 = xn1;
  pa.hn1 = hn1;
  pa.ch1 = ch1;
  pa.o0 = o0;
  pa.o1 = o1;
  pa.bhi0 = W(3);
  pa.bcho0 = W(9);
  pa.bhi1 = W(14);
  pa.bcho1 = W(20);
  pa.out = out;
  pa.ctl = ctl;
  eltm_p<<<NB_, 512, 98304, stream>>>(pa);

  eltm_kLN<<<16384, 256, 0, stream>>>(out, W(23), W(24));
#undef W
}